// Round 14
// baseline (526.815 us; speedup 1.0000x reference)
//
#include <hip/hip_runtime.h>

typedef float f4v __attribute__((ext_vector_type(4)));

#define LOG2E 1.4426950408889634f
#define LN2   0.6931471805599453
#define PSEG  16
#define BURN  16

// Segmented-parallel CRF forward pass. Each sequence is split into 16 segments
// run by independent waves (8192 waves = 8/SIMD, the hardware max -- the TLP
// that fills the readlane/load stall bubbles R6-R12 proved un-fillable
// in-wave; R13 confirmed with PSEG=8: 55% VALUBusy, dur 187->130us).
// Segments p>0 start from an all-ones seed and run 16 burn-in steps: the
// per-step map is a Hilbert-metric contraction (kappa<=tanh(0.1)~0.1, diag
// isometry), so direction error after burn-in is < 1e-15 -- beyond f32.
// Segment p then measures its span's log2 growth G_p (exact power-of-2 renorm
// bookkeeping + one log2 at each end); sum_p G_p telescopes to log2 Z.
// Kernel 2 sums the 16 partials and subtracts the gold score.
// VGPR must stay <= 64 for 8 waves/SIMD: enforced via __launch_bounds__(64,8).

#define RL(uu,k) __uint_as_float((unsigned)__builtin_amdgcn_readlane((int)(uu),(k)))

#define MVG(r, ev) do { \
    float q0 = RL(uu, 4*(r) + 0); \
    float q1 = RL(uu, 4*(r) + 1); \
    float q2 = RL(uu, 4*(r) + 2); \
    float q3 = RL(uu, 4*(r) + 3); \
    s0 = fmaf(q0, (ev).x, s0); \
    s1 = fmaf(q1, (ev).y, s1); \
    s2 = fmaf(q2, (ev).z, s2); \
    s3 = fmaf(q3, (ev).w, s3); \
} while (0)

#define STEPL(lv) do { \
    float el = __builtin_amdgcn_exp2f((lv) * LOG2E); \
    unsigned uu = __float_as_uint(u); \
    float s0 = 0.f, s1 = 0.f, s2 = 0.f, s3 = 0.f; \
    MVG(0,e0);  MVG(1,e1);  MVG(2,e2);  MVG(3,e3); \
    MVG(4,e4);  MVG(5,e5);  MVG(6,e6);  MVG(7,e7); \
    MVG(8,e8);  MVG(9,e9);  MVG(10,e10); MVG(11,e11); \
    MVG(12,e12); MVG(13,e13); MVG(14,e14); MVG(15,e15); \
    u = ((s0 + s1) + (s2 + s3)) * el; \
} while (0)

#define RENORM() do { \
    unsigned E_ = ((unsigned)__builtin_amdgcn_readfirstlane((int)__float_as_uint(u))) >> 23; \
    u *= __uint_as_float((254u - E_) << 23); \
    M2i += (int)E_ - 127; \
} while (0)

#define LOADE(r, ev) do { \
    (ev).x = __builtin_amdgcn_exp2f(Tm[j*L + 4*(r) + 0] * LOG2E) * SC; \
    (ev).y = __builtin_amdgcn_exp2f(Tm[j*L + 4*(r) + 1] * LOG2E) * SC; \
    (ev).z = __builtin_amdgcn_exp2f(Tm[j*L + 4*(r) + 2] * LOG2E) * SC; \
    (ev).w = __builtin_amdgcn_exp2f(Tm[j*L + 4*(r) + 3] * LOG2E) * SC; \
} while (0)

#define LG(t) lg[(size_t)(t) * 64 + j]

#define WSUM(x) do { _Pragma("unroll") \
    for (int off_ = 32; off_; off_ >>= 1) (x) += __shfl_xor((x), off_); } while (0)

__global__ __launch_bounds__(64, 8)
void crf_seg_kernel(const float* __restrict__ logits,
                    const float* __restrict__ Tm,
                    const int*   __restrict__ mask_g,
                    double*      __restrict__ ws,
                    int S)
{
    const int blk = blockIdx.x;
    const int b   = blk >> 4;
    const int p   = blk & 15;
    const int j   = threadIdx.x;       // 0..63, owns state j
    constexpr int L = 66, START = 64, END = 65;
    const float SC = 0.0078125f;       // 2^-7, exact

    const float* lg  = logits + (size_t)b * S * 64;
    const int*   msk = mask_g + (size_t)b * S;

    // sequence length (mask is a prefix of ones)
    int lensum = 0;
    #pragma unroll 4
    for (int t0 = j; t0 < S; t0 += 64) lensum += msk[t0];
    WSUM(lensum);
    const int len = lensum;
    const int NP  = len - 1;                 // steps t = 1..NP
    const int sp  = (p * NP) >> 4;           // segment span (sp, sp1]
    const int sp1 = ((p + 1) * NP) >> 4;

    // transition table (row j), prescaled by 2^-7
    f4v e0,e1,e2,e3,e4,e5,e6,e7,e8,e9,e10,e11,e12,e13,e14,e15;
    LOADE(0,e0);  LOADE(1,e1);  LOADE(2,e2);  LOADE(3,e3);
    LOADE(4,e4);  LOADE(5,e5);  LOADE(6,e6);  LOADE(7,e7);
    LOADE(8,e8);  LOADE(9,e9);  LOADE(10,e10); LOADE(11,e11);
    LOADE(12,e12); LOADE(13,e13); LOADE(14,e14); LOADE(15,e15);

    float u;
    int   M2i = 0;
    float s_start = 1.0f;

    if (p == 0) {
        u = __builtin_amdgcn_exp2f((lg[j] + Tm[j * L + START]) * LOG2E);
    } else {
        // burn-in: 16 steps t = sp-15 .. sp from all-ones seed
        u = 1.0f;
        const int tb = sp - BURN + 1;
        float B0=LG(tb+0),  B1=LG(tb+1),  B2=LG(tb+2),  B3=LG(tb+3);
        float B4=LG(tb+4),  B5=LG(tb+5),  B6=LG(tb+6),  B7=LG(tb+7);
        float B8=LG(tb+8),  B9=LG(tb+9),  B10=LG(tb+10), B11=LG(tb+11);
        float B12=LG(tb+12), B13=LG(tb+13), B14=LG(tb+14), B15=LG(tb+15);
        STEPL(B0);  STEPL(B1);  STEPL(B2);  STEPL(B3);  RENORM();
        STEPL(B4);  STEPL(B5);  STEPL(B6);  STEPL(B7);  RENORM();
        STEPL(B8);  STEPL(B9);  STEPL(B10); STEPL(B11); RENORM();
        STEPL(B12); STEPL(B13); STEPL(B14); STEPL(B15); RENORM();
        M2i = 0;                             // burn-in scale is discarded
        float v = u; WSUM(v); s_start = v;   // reference scale at position sp
    }

    // measured span: n steps t = sp+1 .. sp1, renorm every 4
    const int n = sp1 - sp;
    int t = sp + 1;
    const int ngrp = n >> 2, remn = n & 3;
    float A0 = 0.f, A1 = 0.f, A2 = 0.f, A3 = 0.f;
    if (n > 0) {
        A0 = LG(t);
        A1 = (n > 1) ? LG(t + 1) : 0.f;
        A2 = (n > 2) ? LG(t + 2) : 0.f;
        A3 = (n > 3) ? LG(t + 3) : 0.f;
    }
    #pragma clang loop unroll(disable)
    for (int g = 0; g < ngrp; ++g) {
        const int tn = t + 4;
        int c0 = tn,     c1 = tn + 1, c2 = tn + 2, c3 = tn + 3;
        c0 = (c0 > NP) ? NP : c0; c1 = (c1 > NP) ? NP : c1;
        c2 = (c2 > NP) ? NP : c2; c3 = (c3 > NP) ? NP : c3;
        float N0 = LG(c0), N1 = LG(c1), N2 = LG(c2), N3 = LG(c3);
        STEPL(A0); STEPL(A1); STEPL(A2); STEPL(A3);
        RENORM();
        A0 = N0; A1 = N1; A2 = N2; A3 = N3;
        t = tn;
    }
    if (remn > 0) STEPL(A0);
    if (remn > 1) STEPL(A1);
    if (remn > 2) STEPL(A2);

    // G_p = measured log2 growth (+ final combine for last segment,
    //       + absolute scale for segment 0)
    double G = (double)M2i + 7.0 * (double)n;
    if (p == PSEG - 1) {
        float fv = u * __builtin_amdgcn_exp2f(Tm[END * L + j] * LOG2E);
        WSUM(fv);
        G += (double)__builtin_amdgcn_logf(fv);      // log2
    } else {
        float se = u;
        WSUM(se);
        G += (double)__builtin_amdgcn_logf(se);
    }
    if (p > 0) G -= (double)__builtin_amdgcn_logf(s_start);
    if (j == 0) ws[(size_t)b * PSEG + p] = G;
}

// gold score + combine the 16 partials
__global__ __launch_bounds__(64, 4)
void crf_fin_kernel(const float* __restrict__ logits,
                    const float* __restrict__ Tm,
                    const int*   __restrict__ labels,
                    const int*   __restrict__ mask_g,
                    const double* __restrict__ ws,
                    float* __restrict__ out,
                    int S)
{
    const int b = blockIdx.x;
    const int j = threadIdx.x;
    constexpr int L = 66, START = 64, END = 65;
    const float* lg  = logits + (size_t)b * S * 64;
    const int*   lab = labels + (size_t)b * S;
    const int*   msk = mask_g + (size_t)b * S;

    int   lensum = 0;
    float gsum   = 0.0f;
    #pragma unroll 4
    for (int t0 = j; t0 < S; t0 += 64) {
        if (msk[t0]) {
            ++lensum;
            int lc = lab[t0];
            float ga = lg[(size_t)t0 * 64 + lc];
            if (t0 > 0) ga += Tm[lc * L + lab[t0 - 1]];
            gsum += ga;
        }
    }
    WSUM(lensum);
    WSUM(gsum);
    if (j == 0) {
        const int len = lensum;
        double Gt = 0.0;
        #pragma unroll
        for (int q = 0; q < PSEG; ++q) Gt += ws[(size_t)b * PSEG + q];
        int lab0 = lab[0];
        int labl = lab[len - 1];
        float goldall = gsum + Tm[lab0 * L + START] + Tm[END * L + labl];
        out[b] = (float)(Gt * LN2 - (double)goldall);
    }
}

extern "C" void kernel_launch(void* const* d_in, const int* in_sizes, int n_in,
                              void* d_out, int out_size, void* d_ws, size_t ws_size,
                              hipStream_t stream) {
    const float* logits = (const float*)d_in[0];
    const float* Tm     = (const float*)d_in[1];
    const int*   labels = (const int*)d_in[2];
    const int*   mask   = (const int*)d_in[3];
    float*       out    = (float*)d_out;
    double*      ws     = (double*)d_ws;

    const int B = out_size;                 // 512
    const int S = in_sizes[2] / B;          // 1024

    crf_seg_kernel<<<dim3(B * PSEG), dim3(64), 0, stream>>>(logits, Tm, mask, ws, S);
    crf_fin_kernel<<<dim3(B), dim3(64), 0, stream>>>(logits, Tm, labels, mask, ws, out, S);
}

// Round 15
// 135.747 us; speedup vs baseline: 3.8809x; 3.8809x over previous
//
#include <hip/hip_runtime.h>

typedef float f4v __attribute__((ext_vector_type(4)));

#define LOG2E 1.4426950408889634f
#define LN2   0.6931471805599453
#define PSEG  16
#define BURN  16

// Segmented-parallel CRF forward pass. Each sequence is split into 16 segments
// run by independent waves (8192 waves = 8/SIMD grid-side). R13 (PSEG=8,
// 4 waves/SIMD) confirmed TLP fills the per-wave stall bubbles: 55% VALUBusy,
// 187->130us. R14 showed launch_bounds(64,8) forces VGPR=32 -> eT spills ->
// 1.3GB scratch traffic, 527us. So: launch_bounds(64,4) (R13's config, VGPR=56
// <= 64) -- the HARDWARE can still co-schedule 8 waves/SIMD since 56<=64; the
// bound only floors the allocator, it does not cap runtime occupancy.
// Segments p>0 start from an all-ones seed and run 16 burn-in steps (Hilbert
// contraction kappa~0.1 => direction error <1e-15, beyond f32). Segment p
// measures its span's log2 growth G_p (exact power-of-2 renorm bookkeeping +
// one log2 at each end); sum_p G_p telescopes to log2 Z. Kernel 2 sums the
// partials and subtracts the gold score.

#define RL(uu,k) __uint_as_float((unsigned)__builtin_amdgcn_readlane((int)(uu),(k)))

#define MVG(r, ev) do { \
    float q0 = RL(uu, 4*(r) + 0); \
    float q1 = RL(uu, 4*(r) + 1); \
    float q2 = RL(uu, 4*(r) + 2); \
    float q3 = RL(uu, 4*(r) + 3); \
    s0 = fmaf(q0, (ev).x, s0); \
    s1 = fmaf(q1, (ev).y, s1); \
    s2 = fmaf(q2, (ev).z, s2); \
    s3 = fmaf(q3, (ev).w, s3); \
} while (0)

#define STEPL(lv) do { \
    float el = __builtin_amdgcn_exp2f((lv) * LOG2E); \
    unsigned uu = __float_as_uint(u); \
    float s0 = 0.f, s1 = 0.f, s2 = 0.f, s3 = 0.f; \
    MVG(0,e0);  MVG(1,e1);  MVG(2,e2);  MVG(3,e3); \
    MVG(4,e4);  MVG(5,e5);  MVG(6,e6);  MVG(7,e7); \
    MVG(8,e8);  MVG(9,e9);  MVG(10,e10); MVG(11,e11); \
    MVG(12,e12); MVG(13,e13); MVG(14,e14); MVG(15,e15); \
    u = ((s0 + s1) + (s2 + s3)) * el; \
} while (0)

#define RENORM() do { \
    unsigned E_ = ((unsigned)__builtin_amdgcn_readfirstlane((int)__float_as_uint(u))) >> 23; \
    u *= __uint_as_float((254u - E_) << 23); \
    M2i += (int)E_ - 127; \
} while (0)

#define LOADE(r, ev) do { \
    (ev).x = __builtin_amdgcn_exp2f(Tm[j*L + 4*(r) + 0] * LOG2E) * SC; \
    (ev).y = __builtin_amdgcn_exp2f(Tm[j*L + 4*(r) + 1] * LOG2E) * SC; \
    (ev).z = __builtin_amdgcn_exp2f(Tm[j*L + 4*(r) + 2] * LOG2E) * SC; \
    (ev).w = __builtin_amdgcn_exp2f(Tm[j*L + 4*(r) + 3] * LOG2E) * SC; \
} while (0)

#define LG(t) lg[(size_t)(t) * 64 + j]

#define WSUM(x) do { _Pragma("unroll") \
    for (int off_ = 32; off_; off_ >>= 1) (x) += __shfl_xor((x), off_); } while (0)

__global__ __launch_bounds__(64, 4)
void crf_seg_kernel(const float* __restrict__ logits,
                    const float* __restrict__ Tm,
                    const int*   __restrict__ mask_g,
                    double*      __restrict__ ws,
                    int S)
{
    const int blk = blockIdx.x;
    const int b   = blk >> 4;
    const int p   = blk & 15;
    const int j   = threadIdx.x;       // 0..63, owns state j
    constexpr int L = 66, START = 64, END = 65;
    const float SC = 0.0078125f;       // 2^-7, exact

    const float* lg  = logits + (size_t)b * S * 64;
    const int*   msk = mask_g + (size_t)b * S;

    // sequence length (mask is a prefix of ones)
    int lensum = 0;
    #pragma unroll 4
    for (int t0 = j; t0 < S; t0 += 64) lensum += msk[t0];
    WSUM(lensum);
    const int len = lensum;
    const int NP  = len - 1;                 // steps t = 1..NP
    const int sp  = (p * NP) >> 4;           // segment span (sp, sp1]
    const int sp1 = ((p + 1) * NP) >> 4;

    // transition table (row j), prescaled by 2^-7
    f4v e0,e1,e2,e3,e4,e5,e6,e7,e8,e9,e10,e11,e12,e13,e14,e15;
    LOADE(0,e0);  LOADE(1,e1);  LOADE(2,e2);  LOADE(3,e3);
    LOADE(4,e4);  LOADE(5,e5);  LOADE(6,e6);  LOADE(7,e7);
    LOADE(8,e8);  LOADE(9,e9);  LOADE(10,e10); LOADE(11,e11);
    LOADE(12,e12); LOADE(13,e13); LOADE(14,e14); LOADE(15,e15);

    float u;
    int   M2i = 0;
    float s_start = 1.0f;

    if (p == 0) {
        u = __builtin_amdgcn_exp2f((lg[j] + Tm[j * L + START]) * LOG2E);
    } else {
        // burn-in: 16 steps t = sp-15 .. sp from all-ones seed
        u = 1.0f;
        const int tb = sp - BURN + 1;
        float B0=LG(tb+0),  B1=LG(tb+1),  B2=LG(tb+2),  B3=LG(tb+3);
        float B4=LG(tb+4),  B5=LG(tb+5),  B6=LG(tb+6),  B7=LG(tb+7);
        float B8=LG(tb+8),  B9=LG(tb+9),  B10=LG(tb+10), B11=LG(tb+11);
        float B12=LG(tb+12), B13=LG(tb+13), B14=LG(tb+14), B15=LG(tb+15);
        STEPL(B0);  STEPL(B1);  STEPL(B2);  STEPL(B3);  RENORM();
        STEPL(B4);  STEPL(B5);  STEPL(B6);  STEPL(B7);  RENORM();
        STEPL(B8);  STEPL(B9);  STEPL(B10); STEPL(B11); RENORM();
        STEPL(B12); STEPL(B13); STEPL(B14); STEPL(B15); RENORM();
        M2i = 0;                             // burn-in scale is discarded
        float v = u; WSUM(v); s_start = v;   // reference scale at position sp
    }

    // measured span: n steps t = sp+1 .. sp1, renorm every 4
    const int n = sp1 - sp;
    int t = sp + 1;
    const int ngrp = n >> 2, remn = n & 3;
    float A0 = 0.f, A1 = 0.f, A2 = 0.f, A3 = 0.f;
    if (n > 0) {
        A0 = LG(t);
        A1 = (n > 1) ? LG(t + 1) : 0.f;
        A2 = (n > 2) ? LG(t + 2) : 0.f;
        A3 = (n > 3) ? LG(t + 3) : 0.f;
    }
    #pragma clang loop unroll(disable)
    for (int g = 0; g < ngrp; ++g) {
        const int tn = t + 4;
        int c0 = tn,     c1 = tn + 1, c2 = tn + 2, c3 = tn + 3;
        c0 = (c0 > NP) ? NP : c0; c1 = (c1 > NP) ? NP : c1;
        c2 = (c2 > NP) ? NP : c2; c3 = (c3 > NP) ? NP : c3;
        float N0 = LG(c0), N1 = LG(c1), N2 = LG(c2), N3 = LG(c3);
        STEPL(A0); STEPL(A1); STEPL(A2); STEPL(A3);
        RENORM();
        A0 = N0; A1 = N1; A2 = N2; A3 = N3;
        t = tn;
    }
    if (remn > 0) STEPL(A0);
    if (remn > 1) STEPL(A1);
    if (remn > 2) STEPL(A2);

    // G_p = measured log2 growth (+ final combine for last segment,
    //       + absolute scale for segment 0)
    double G = (double)M2i + 7.0 * (double)n;
    if (p == PSEG - 1) {
        float fv = u * __builtin_amdgcn_exp2f(Tm[END * L + j] * LOG2E);
        WSUM(fv);
        G += (double)__builtin_amdgcn_logf(fv);      // log2
    } else {
        float se = u;
        WSUM(se);
        G += (double)__builtin_amdgcn_logf(se);
    }
    if (p > 0) G -= (double)__builtin_amdgcn_logf(s_start);
    if (j == 0) ws[(size_t)b * PSEG + p] = G;
}

// gold score + combine the 16 partials
__global__ __launch_bounds__(64, 4)
void crf_fin_kernel(const float* __restrict__ logits,
                    const float* __restrict__ Tm,
                    const int*   __restrict__ labels,
                    const int*   __restrict__ mask_g,
                    const double* __restrict__ ws,
                    float* __restrict__ out,
                    int S)
{
    const int b = blockIdx.x;
    const int j = threadIdx.x;
    constexpr int L = 66, START = 64, END = 65;
    const float* lg  = logits + (size_t)b * S * 64;
    const int*   lab = labels + (size_t)b * S;
    const int*   msk = mask_g + (size_t)b * S;

    int   lensum = 0;
    float gsum   = 0.0f;
    #pragma unroll 4
    for (int t0 = j; t0 < S; t0 += 64) {
        if (msk[t0]) {
            ++lensum;
            int lc = lab[t0];
            float ga = lg[(size_t)t0 * 64 + lc];
            if (t0 > 0) ga += Tm[lc * L + lab[t0 - 1]];
            gsum += ga;
        }
    }
    WSUM(lensum);
    WSUM(gsum);
    if (j == 0) {
        const int len = lensum;
        double Gt = 0.0;
        #pragma unroll
        for (int q = 0; q < PSEG; ++q) Gt += ws[(size_t)b * PSEG + q];
        int lab0 = lab[0];
        int labl = lab[len - 1];
        float goldall = gsum + Tm[lab0 * L + START] + Tm[END * L + labl];
        out[b] = (float)(Gt * LN2 - (double)goldall);
    }
}

extern "C" void kernel_launch(void* const* d_in, const int* in_sizes, int n_in,
                              void* d_out, int out_size, void* d_ws, size_t ws_size,
                              hipStream_t stream) {
    const float* logits = (const float*)d_in[0];
    const float* Tm     = (const float*)d_in[1];
    const int*   labels = (const int*)d_in[2];
    const int*   mask   = (const int*)d_in[3];
    float*       out    = (float*)d_out;
    double*      ws     = (double*)d_ws;

    const int B = out_size;                 // 512
    const int S = in_sizes[2] / B;          // 1024

    crf_seg_kernel<<<dim3(B * PSEG), dim3(64), 0, stream>>>(logits, Tm, mask, ws, S);
    crf_fin_kernel<<<dim3(B), dim3(64), 0, stream>>>(logits, Tm, labels, mask, ws, out, S);
}

// Round 16
// 133.921 us; speedup vs baseline: 3.9338x; 1.0136x over previous
//
#include <hip/hip_runtime.h>

typedef float f4v __attribute__((ext_vector_type(4)));

#define LOG2E 1.4426950408889634f
#define LN2   0.6931471805599453
#define PSEG  16
#define BURN  16

// Segmented-parallel CRF forward pass, 4 segments (waves) per 256-thread
// workgroup. R13/R15 established: TLP fills the per-wave stall bubbles
// (55->62% VALUBusy), but 1-wave workgroups cap residency at ~11 waves/CU
// (occupancy 29-35% despite 8192 waves and VGPR=56) -- the CU workgroup-slot
// limit. Packing 4 independent waves per WG needs only 8 WG-slots/CU for the
// full 32 waves/CU. Waves never interact: no LDS, no __syncthreads, all
// reductions are intra-wave shuffles. Per-wave body identical to R15.
// Segments p>0: all-ones seed + 16 burn-in steps (Hilbert contraction
// kappa~0.1 => direction error <1e-15). Segment p measures its span's log2
// growth G_p (exact power-of-2 renorm bookkeeping + one log2 at each end);
// sum_p G_p telescopes to log2 Z. Kernel 2 sums partials minus gold score.

#define RL(uu,k) __uint_as_float((unsigned)__builtin_amdgcn_readlane((int)(uu),(k)))

#define MVG(r, ev) do { \
    float q0 = RL(uu, 4*(r) + 0); \
    float q1 = RL(uu, 4*(r) + 1); \
    float q2 = RL(uu, 4*(r) + 2); \
    float q3 = RL(uu, 4*(r) + 3); \
    s0 = fmaf(q0, (ev).x, s0); \
    s1 = fmaf(q1, (ev).y, s1); \
    s2 = fmaf(q2, (ev).z, s2); \
    s3 = fmaf(q3, (ev).w, s3); \
} while (0)

#define STEPL(lv) do { \
    float el = __builtin_amdgcn_exp2f((lv) * LOG2E); \
    unsigned uu = __float_as_uint(u); \
    float s0 = 0.f, s1 = 0.f, s2 = 0.f, s3 = 0.f; \
    MVG(0,e0);  MVG(1,e1);  MVG(2,e2);  MVG(3,e3); \
    MVG(4,e4);  MVG(5,e5);  MVG(6,e6);  MVG(7,e7); \
    MVG(8,e8);  MVG(9,e9);  MVG(10,e10); MVG(11,e11); \
    MVG(12,e12); MVG(13,e13); MVG(14,e14); MVG(15,e15); \
    u = ((s0 + s1) + (s2 + s3)) * el; \
} while (0)

#define RENORM() do { \
    unsigned E_ = ((unsigned)__builtin_amdgcn_readfirstlane((int)__float_as_uint(u))) >> 23; \
    u *= __uint_as_float((254u - E_) << 23); \
    M2i += (int)E_ - 127; \
} while (0)

#define LOADE(r, ev) do { \
    (ev).x = __builtin_amdgcn_exp2f(Tm[j*L + 4*(r) + 0] * LOG2E) * SC; \
    (ev).y = __builtin_amdgcn_exp2f(Tm[j*L + 4*(r) + 1] * LOG2E) * SC; \
    (ev).z = __builtin_amdgcn_exp2f(Tm[j*L + 4*(r) + 2] * LOG2E) * SC; \
    (ev).w = __builtin_amdgcn_exp2f(Tm[j*L + 4*(r) + 3] * LOG2E) * SC; \
} while (0)

#define LG(t) lg[(size_t)(t) * 64 + j]

#define WSUM(x) do { _Pragma("unroll") \
    for (int off_ = 32; off_; off_ >>= 1) (x) += __shfl_xor((x), off_); } while (0)

__global__ __launch_bounds__(256, 4)
void crf_seg_kernel(const float* __restrict__ logits,
                    const float* __restrict__ Tm,
                    const int*   __restrict__ mask_g,
                    double*      __restrict__ ws,
                    int S)
{
    const int blk = blockIdx.x;
    const int wid = threadIdx.x >> 6;          // wave in block: 0..3
    const int j   = threadIdx.x & 63;          // lane, owns state j
    const int b   = blk >> 2;                  // sequence
    const int p   = ((blk & 3) << 2) | wid;    // segment 0..15
    constexpr int L = 66, START = 64, END = 65;
    const float SC = 0.0078125f;       // 2^-7, exact

    const float* lg  = logits + (size_t)b * S * 64;
    const int*   msk = mask_g + (size_t)b * S;

    // sequence length (mask is a prefix of ones)
    int lensum = 0;
    #pragma unroll 4
    for (int t0 = j; t0 < S; t0 += 64) lensum += msk[t0];
    WSUM(lensum);
    const int len = lensum;
    const int NP  = len - 1;                 // steps t = 1..NP
    const int sp  = (p * NP) >> 4;           // segment span (sp, sp1]
    const int sp1 = ((p + 1) * NP) >> 4;

    // transition table (row j), prescaled by 2^-7
    f4v e0,e1,e2,e3,e4,e5,e6,e7,e8,e9,e10,e11,e12,e13,e14,e15;
    LOADE(0,e0);  LOADE(1,e1);  LOADE(2,e2);  LOADE(3,e3);
    LOADE(4,e4);  LOADE(5,e5);  LOADE(6,e6);  LOADE(7,e7);
    LOADE(8,e8);  LOADE(9,e9);  LOADE(10,e10); LOADE(11,e11);
    LOADE(12,e12); LOADE(13,e13); LOADE(14,e14); LOADE(15,e15);

    float u;
    int   M2i = 0;
    float s_start = 1.0f;

    if (p == 0) {
        u = __builtin_amdgcn_exp2f((lg[j] + Tm[j * L + START]) * LOG2E);
    } else {
        // burn-in: 16 steps t = sp-15 .. sp from all-ones seed
        u = 1.0f;
        const int tb = sp - BURN + 1;
        float B0=LG(tb+0),  B1=LG(tb+1),  B2=LG(tb+2),  B3=LG(tb+3);
        float B4=LG(tb+4),  B5=LG(tb+5),  B6=LG(tb+6),  B7=LG(tb+7);
        float B8=LG(tb+8),  B9=LG(tb+9),  B10=LG(tb+10), B11=LG(tb+11);
        float B12=LG(tb+12), B13=LG(tb+13), B14=LG(tb+14), B15=LG(tb+15);
        STEPL(B0);  STEPL(B1);  STEPL(B2);  STEPL(B3);  RENORM();
        STEPL(B4);  STEPL(B5);  STEPL(B6);  STEPL(B7);  RENORM();
        STEPL(B8);  STEPL(B9);  STEPL(B10); STEPL(B11); RENORM();
        STEPL(B12); STEPL(B13); STEPL(B14); STEPL(B15); RENORM();
        M2i = 0;                             // burn-in scale is discarded
        float v = u; WSUM(v); s_start = v;   // reference scale at position sp
    }

    // measured span: n steps t = sp+1 .. sp1, renorm every 4
    const int n = sp1 - sp;
    int t = sp + 1;
    const int ngrp = n >> 2, remn = n & 3;
    float A0 = 0.f, A1 = 0.f, A2 = 0.f, A3 = 0.f;
    if (n > 0) {
        A0 = LG(t);
        A1 = (n > 1) ? LG(t + 1) : 0.f;
        A2 = (n > 2) ? LG(t + 2) : 0.f;
        A3 = (n > 3) ? LG(t + 3) : 0.f;
    }
    #pragma clang loop unroll(disable)
    for (int g = 0; g < ngrp; ++g) {
        const int tn = t + 4;
        int c0 = tn,     c1 = tn + 1, c2 = tn + 2, c3 = tn + 3;
        c0 = (c0 > NP) ? NP : c0; c1 = (c1 > NP) ? NP : c1;
        c2 = (c2 > NP) ? NP : c2; c3 = (c3 > NP) ? NP : c3;
        float N0 = LG(c0), N1 = LG(c1), N2 = LG(c2), N3 = LG(c3);
        STEPL(A0); STEPL(A1); STEPL(A2); STEPL(A3);
        RENORM();
        A0 = N0; A1 = N1; A2 = N2; A3 = N3;
        t = tn;
    }
    if (remn > 0) STEPL(A0);
    if (remn > 1) STEPL(A1);
    if (remn > 2) STEPL(A2);

    // G_p = measured log2 growth (+ final combine for last segment,
    //       + absolute scale for segment 0)
    double G = (double)M2i + 7.0 * (double)n;
    if (p == PSEG - 1) {
        float fv = u * __builtin_amdgcn_exp2f(Tm[END * L + j] * LOG2E);
        WSUM(fv);
        G += (double)__builtin_amdgcn_logf(fv);      // log2
    } else {
        float se = u;
        WSUM(se);
        G += (double)__builtin_amdgcn_logf(se);
    }
    if (p > 0) G -= (double)__builtin_amdgcn_logf(s_start);
    if (j == 0) ws[(size_t)b * PSEG + p] = G;
}

// gold score + combine the 16 partials; 4 sequences per block (1 per wave)
__global__ __launch_bounds__(256, 4)
void crf_fin_kernel(const float* __restrict__ logits,
                    const float* __restrict__ Tm,
                    const int*   __restrict__ labels,
                    const int*   __restrict__ mask_g,
                    const double* __restrict__ ws,
                    float* __restrict__ out,
                    int S, int B)
{
    const int wid = threadIdx.x >> 6;
    const int j   = threadIdx.x & 63;
    const int b   = (blockIdx.x << 2) | wid;
    if (b >= B) return;
    constexpr int L = 66, START = 64, END = 65;
    const float* lg  = logits + (size_t)b * S * 64;
    const int*   lab = labels + (size_t)b * S;
    const int*   msk = mask_g + (size_t)b * S;

    int   lensum = 0;
    float gsum   = 0.0f;
    #pragma unroll 4
    for (int t0 = j; t0 < S; t0 += 64) {
        if (msk[t0]) {
            ++lensum;
            int lc = lab[t0];
            float ga = lg[(size_t)t0 * 64 + lc];
            if (t0 > 0) ga += Tm[lc * L + lab[t0 - 1]];
            gsum += ga;
        }
    }
    WSUM(lensum);
    WSUM(gsum);
    if (j == 0) {
        const int len = lensum;
        double Gt = 0.0;
        #pragma unroll
        for (int q = 0; q < PSEG; ++q) Gt += ws[(size_t)b * PSEG + q];
        int lab0 = lab[0];
        int labl = lab[len - 1];
        float goldall = gsum + Tm[lab0 * L + START] + Tm[END * L + labl];
        out[b] = (float)(Gt * LN2 - (double)goldall);
    }
}

extern "C" void kernel_launch(void* const* d_in, const int* in_sizes, int n_in,
                              void* d_out, int out_size, void* d_ws, size_t ws_size,
                              hipStream_t stream) {
    const float* logits = (const float*)d_in[0];
    const float* Tm     = (const float*)d_in[1];
    const int*   labels = (const int*)d_in[2];
    const int*   mask   = (const int*)d_in[3];
    float*       out    = (float*)d_out;
    double*      ws     = (double*)d_ws;

    const int B = out_size;                 // 512
    const int S = in_sizes[2] / B;          // 1024

    crf_seg_kernel<<<dim3(B * (PSEG / 4)), dim3(256), 0, stream>>>(logits, Tm, mask, ws, S);
    crf_fin_kernel<<<dim3((B + 3) / 4), dim3(256), 0, stream>>>(logits, Tm, labels, mask, ws, out, S, B);
}

// Round 17
// 107.318 us; speedup vs baseline: 4.9089x; 1.2479x over previous
//
#include <hip/hip_runtime.h>

typedef float f2 __attribute__((ext_vector_type(2)));

#define LOG2E 1.4426950408889634f
#define LN2   0.6931471805599453
#define PSEG  16
#define BURN  16

// Segmented-parallel CRF forward pass, 4 segments (waves) per 256-thread WG,
// with R4's instruction-minimal LDS-broadcast step body.
// History: R13/R15/R16 proved TLP fills per-wave stalls, but rocprof showed
// ~220 VALU instr/step (VGPR=48 -> eT table NOT resident; remat pathology of
// R9 returned). R4's LDS-broadcast + v_pk_fma_f32 body measured ~64 VALU
// instr/step with the table resident at VGPR=64 -- its LDS-latency stall is
// exactly what multiwave TLP hides. Broadcast reads are same-address across
// the wave (bank-conflict-free, dedup'd by the LDS crossbar).
// Per-wave Ubuf slot: no cross-wave sync (lgkmcnt only, same-wave order).
// Segments p>0: all-ones seed + 16 burn-in steps (Hilbert contraction
// kappa<=tanh(0.1) => direction error <1e-15, beyond f32). Segment p measures
// its span's log2 growth G_p (exact power-of-2 renorm bookkeeping + one log2
// at each end); sum_p G_p telescopes to log2 Z. Kernel 2: partials - gold.

#define RENORM() do { \
    unsigned E_ = ((unsigned)__builtin_amdgcn_readfirstlane((int)__float_as_uint(u))) >> 23; \
    u *= __uint_as_float((254u - E_) << 23); \
    M2i += (int)E_ - 127; \
} while (0)

// one recursion step: LDS broadcast of u + 32 packed FMAs against eT
#define STEPL(lv) do { \
    Ubuf[wid][j] = u; \
    asm volatile("s_waitcnt lgkmcnt(0)" ::: "memory"); \
    float el = __builtin_amdgcn_exp2f((lv) * LOG2E); \
    const float4* U4 = (const float4*)(&Ubuf[wid][0]); \
    f2 a0={0.f,0.f}, a1={0.f,0.f}, a2={0.f,0.f}, a3={0.f,0.f}; \
    _Pragma("unroll") \
    for (int i_ = 0; i_ < 8; ++i_) { \
        float4 p_ = U4[2*i_]; \
        float4 q_ = U4[2*i_+1]; \
        f2 p0_ = {p_.x, p_.y}, p1_ = {p_.z, p_.w}; \
        f2 q0_ = {q_.x, q_.y}, q1_ = {q_.z, q_.w}; \
        a0 = __builtin_elementwise_fma(p0_, eT[4*i_+0], a0); \
        a1 = __builtin_elementwise_fma(p1_, eT[4*i_+1], a1); \
        a2 = __builtin_elementwise_fma(q0_, eT[4*i_+2], a2); \
        a3 = __builtin_elementwise_fma(q1_, eT[4*i_+3], a3); \
    } \
    f2 s01_ = a0 + a1, s23_ = a2 + a3, sv_ = s01_ + s23_; \
    u = (sv_.x + sv_.y) * el; \
} while (0)

#define LG(t) lg[(size_t)(t) * 64 + j]

#define WSUM(x) do { _Pragma("unroll") \
    for (int off_ = 32; off_; off_ >>= 1) (x) += __shfl_xor((x), off_); } while (0)

__global__ __launch_bounds__(256, 4)
void crf_seg_kernel(const float* __restrict__ logits,
                    const float* __restrict__ Tm,
                    const int*   __restrict__ mask_g,
                    double*      __restrict__ ws,
                    int S)
{
    const int blk = blockIdx.x;
    const int wid = threadIdx.x >> 6;          // wave in block: 0..3
    const int j   = threadIdx.x & 63;          // lane, owns state j
    const int b   = blk >> 2;                  // sequence
    const int p   = ((blk & 3) << 2) | wid;    // segment 0..15
    constexpr int L = 66, START = 64, END = 65;
    const float SC = 0.0078125f;               // 2^-7, exact

    __shared__ __align__(16) float Ubuf[4][64];   // per-wave broadcast slot

    const float* lg  = logits + (size_t)b * S * 64;
    const int*   msk = mask_g + (size_t)b * S;

    // sequence length (mask is a prefix of ones)
    int lensum = 0;
    #pragma unroll 4
    for (int t0 = j; t0 < S; t0 += 64) lensum += msk[t0];
    WSUM(lensum);
    const int len = lensum;
    const int NP  = len - 1;                 // steps t = 1..NP
    const int sp  = (p * NP) >> 4;           // segment span (sp, sp1]
    const int sp1 = ((p + 1) * NP) >> 4;

    // transition table, row j, prescaled by 2^-7: eT[m] = {e^T[j][2m], e^T[j][2m+1]}
    f2 eT[32];
    #pragma unroll
    for (int r = 0; r < 32; ++r) {
        f2 v = { __builtin_amdgcn_exp2f(Tm[j * L + 2*r]     * LOG2E) * SC,
                 __builtin_amdgcn_exp2f(Tm[j * L + 2*r + 1] * LOG2E) * SC };
        eT[r] = v;
    }

    float u;
    int   M2i = 0;
    float s_start = 1.0f;

    if (p == 0) {
        u = __builtin_amdgcn_exp2f((lg[j] + Tm[j * L + START]) * LOG2E);
    } else {
        // burn-in: 16 steps t = sp-15 .. sp from all-ones seed
        u = 1.0f;
        const int tb = sp - BURN + 1;
        float B0=LG(tb+0),  B1=LG(tb+1),  B2=LG(tb+2),  B3=LG(tb+3);
        float B4=LG(tb+4),  B5=LG(tb+5),  B6=LG(tb+6),  B7=LG(tb+7);
        float B8=LG(tb+8),  B9=LG(tb+9),  B10=LG(tb+10), B11=LG(tb+11);
        float B12=LG(tb+12), B13=LG(tb+13), B14=LG(tb+14), B15=LG(tb+15);
        STEPL(B0);  STEPL(B1);  STEPL(B2);  STEPL(B3);  RENORM();
        STEPL(B4);  STEPL(B5);  STEPL(B6);  STEPL(B7);  RENORM();
        STEPL(B8);  STEPL(B9);  STEPL(B10); STEPL(B11); RENORM();
        STEPL(B12); STEPL(B13); STEPL(B14); STEPL(B15); RENORM();
        M2i = 0;                             // burn-in scale is discarded
        float v = u; WSUM(v); s_start = v;   // reference scale at position sp
    }

    // measured span: n steps t = sp+1 .. sp1, renorm every 4
    const int n = sp1 - sp;
    int t = sp + 1;
    const int ngrp = n >> 2, remn = n & 3;
    float A0 = 0.f, A1 = 0.f, A2 = 0.f, A3 = 0.f;
    if (n > 0) {
        A0 = LG(t);
        A1 = (n > 1) ? LG(t + 1) : 0.f;
        A2 = (n > 2) ? LG(t + 2) : 0.f;
        A3 = (n > 3) ? LG(t + 3) : 0.f;
    }
    #pragma clang loop unroll(disable)
    for (int g = 0; g < ngrp; ++g) {
        const int tn = t + 4;
        int c0 = tn,     c1 = tn + 1, c2 = tn + 2, c3 = tn + 3;
        c0 = (c0 > NP) ? NP : c0; c1 = (c1 > NP) ? NP : c1;
        c2 = (c2 > NP) ? NP : c2; c3 = (c3 > NP) ? NP : c3;
        float N0 = LG(c0), N1 = LG(c1), N2 = LG(c2), N3 = LG(c3);
        STEPL(A0); STEPL(A1); STEPL(A2); STEPL(A3);
        RENORM();
        A0 = N0; A1 = N1; A2 = N2; A3 = N3;
        t = tn;
    }
    if (remn > 0) STEPL(A0);
    if (remn > 1) STEPL(A1);
    if (remn > 2) STEPL(A2);

    // G_p = measured log2 growth (+ final combine for last segment,
    //       + absolute scale for segment 0)
    double G = (double)M2i + 7.0 * (double)n;
    if (p == PSEG - 1) {
        float fv = u * __builtin_amdgcn_exp2f(Tm[END * L + j] * LOG2E);
        WSUM(fv);
        G += (double)__builtin_amdgcn_logf(fv);      // log2
    } else {
        float se = u;
        WSUM(se);
        G += (double)__builtin_amdgcn_logf(se);
    }
    if (p > 0) G -= (double)__builtin_amdgcn_logf(s_start);
    if (j == 0) ws[(size_t)b * PSEG + p] = G;
}

// gold score + combine the 16 partials; 4 sequences per block (1 per wave)
__global__ __launch_bounds__(256, 4)
void crf_fin_kernel(const float* __restrict__ logits,
                    const float* __restrict__ Tm,
                    const int*   __restrict__ labels,
                    const int*   __restrict__ mask_g,
                    const double* __restrict__ ws,
                    float* __restrict__ out,
                    int S, int B)
{
    const int wid = threadIdx.x >> 6;
    const int j   = threadIdx.x & 63;
    const int b   = (blockIdx.x << 2) | wid;
    if (b >= B) return;
    constexpr int L = 66, START = 64, END = 65;
    const float* lg  = logits + (size_t)b * S * 64;
    const int*   lab = labels + (size_t)b * S;
    const int*   msk = mask_g + (size_t)b * S;

    int   lensum = 0;
    float gsum   = 0.0f;
    #pragma unroll 4
    for (int t0 = j; t0 < S; t0 += 64) {
        if (msk[t0]) {
            ++lensum;
            int lc = lab[t0];
            float ga = lg[(size_t)t0 * 64 + lc];
            if (t0 > 0) ga += Tm[lc * L + lab[t0 - 1]];
            gsum += ga;
        }
    }
    WSUM(lensum);
    WSUM(gsum);
    if (j == 0) {
        const int len = lensum;
        double Gt = 0.0;
        #pragma unroll
        for (int q = 0; q < PSEG; ++q) Gt += ws[(size_t)b * PSEG + q];
        int lab0 = lab[0];
        int labl = lab[len - 1];
        float goldall = gsum + Tm[lab0 * L + START] + Tm[END * L + labl];
        out[b] = (float)(Gt * LN2 - (double)goldall);
    }
}

extern "C" void kernel_launch(void* const* d_in, const int* in_sizes, int n_in,
                              void* d_out, int out_size, void* d_ws, size_t ws_size,
                              hipStream_t stream) {
    const float* logits = (const float*)d_in[0];
    const float* Tm     = (const float*)d_in[1];
    const int*   labels = (const int*)d_in[2];
    const int*   mask   = (const int*)d_in[3];
    float*       out    = (float*)d_out;
    double*      ws     = (double*)d_ws;

    const int B = out_size;                 // 512
    const int S = in_sizes[2] / B;          // 1024

    crf_seg_kernel<<<dim3(B * (PSEG / 4)), dim3(256), 0, stream>>>(logits, Tm, mask, ws, S);
    crf_fin_kernel<<<dim3((B + 3) / 4), dim3(256), 0, stream>>>(logits, Tm, labels, mask, ws, out, S, B);
}

// Round 19
// 61.603 us; speedup vs baseline: 8.5518x; 1.7421x over previous
//
#include <hip/hip_runtime.h>

typedef float f32x4 __attribute__((ext_vector_type(4)));
typedef short bf16x8 __attribute__((ext_vector_type(8)));

#define LOG2E 1.4426950408889634f
#define LN2   0.6931471805599453
#define PSEG  32
#define BURN  16

// MFMA-batched segmented CRF forward. 1024 waves (1 block = 1 wave), each
// advancing 16 chains (segments) of one sequence through the shared 64x64
// transition matrix with mfma_f32_16x16x32_bf16 (3-product bf16 hi/lo split).
// State U in the verified C/D fragment layout: chain=lane&15, state row =
// (lane>>4)*4+reg, 4 row-tiles. Per step: U -> LDS (stride-68 pad) -> B-frags
// (hi/lo via v_cvt_pk_bf16_f32) -> 24 MFMAs -> *el(logits) -> per-chain
// freeze-mask. Exact power-of-2 renorm every 4 steps (per-chain via
// bpermute); burn-in (16) + span growth telescoped as in R13-R17.
// FIX vs R18: the T[end,:] combine factor targets the LAST NON-EMPTY chain
// (c*n < NP <= (c+1)*n), not c==31 -- with n=ceil(NP/32), trailing chains can
// be empty (their G telescopes to exactly 0; frozen renorms preserve
// log2(Sv)+M2, verified algebraically).

__device__ __forceinline__ unsigned cvtpk(float a, float b) {
    unsigned r;
    asm("v_cvt_pk_bf16_f32 %0, %1, %2" : "=v"(r) : "v"(a), "v"(b));
    return r;
}

union FRAG { unsigned u[4]; bf16x8 s; };

// split 8 f32 (qa=e0..3, qb=e4..7) into hi/lo bf16x8 fragments
#define SPLIT8(qa, qb, FH, FL) do { \
    unsigned h0 = cvtpk((qa).x, (qa).y); \
    unsigned h1 = cvtpk((qa).z, (qa).w); \
    unsigned h2 = cvtpk((qb).x, (qb).y); \
    unsigned h3 = cvtpk((qb).z, (qb).w); \
    float r0 = (qa).x - __uint_as_float(h0 << 16); \
    float r1 = (qa).y - __uint_as_float(h0 & 0xffff0000u); \
    float r2 = (qa).z - __uint_as_float(h1 << 16); \
    float r3 = (qa).w - __uint_as_float(h1 & 0xffff0000u); \
    float r4 = (qb).x - __uint_as_float(h2 << 16); \
    float r5 = (qb).y - __uint_as_float(h2 & 0xffff0000u); \
    float r6 = (qb).z - __uint_as_float(h3 << 16); \
    float r7 = (qb).w - __uint_as_float(h3 & 0xffff0000u); \
    (FH).u[0] = h0; (FH).u[1] = h1; (FH).u[2] = h2; (FH).u[3] = h3; \
    (FL).u[0] = cvtpk(r0, r1); (FL).u[1] = cvtpk(r2, r3); \
    (FL).u[2] = cvtpk(r4, r5); (FL).u[3] = cvtpk(r6, r7); \
} while (0)

// A-fragment (E row-tile mm, k-tile kt), prescaled 2^-7, split hi/lo.
// A layout: row = lane&15 (+16*mm), k = 8*(lane>>4) + e (+32*kt).
#define BUILD_A(mm, kt, FH, FL) do { \
    const int ar = 16*(mm) + cl; \
    const int kb = 32*(kt) + 8*gq; \
    f32x4 qa, qb; \
    qa.x = __builtin_amdgcn_exp2f(Tm[ar*L + kb + 0] * LOG2E) * SC; \
    qa.y = __builtin_amdgcn_exp2f(Tm[ar*L + kb + 1] * LOG2E) * SC; \
    qa.z = __builtin_amdgcn_exp2f(Tm[ar*L + kb + 2] * LOG2E) * SC; \
    qa.w = __builtin_amdgcn_exp2f(Tm[ar*L + kb + 3] * LOG2E) * SC; \
    qb.x = __builtin_amdgcn_exp2f(Tm[ar*L + kb + 4] * LOG2E) * SC; \
    qb.y = __builtin_amdgcn_exp2f(Tm[ar*L + kb + 5] * LOG2E) * SC; \
    qb.z = __builtin_amdgcn_exp2f(Tm[ar*L + kb + 6] * LOG2E) * SC; \
    qb.w = __builtin_amdgcn_exp2f(Tm[ar*L + kb + 7] * LOG2E) * SC; \
    SPLIT8(qa, qb, FH, FL); \
} while (0)

#define EXPV(d, s_) do { \
    (d).x = __builtin_amdgcn_exp2f((s_).x * LOG2E); \
    (d).y = __builtin_amdgcn_exp2f((s_).y * LOG2E); \
    (d).z = __builtin_amdgcn_exp2f((s_).z * LOG2E); \
    (d).w = __builtin_amdgcn_exp2f((s_).w * LOG2E); \
} while (0)

#define MFMA(a_, b_, c_) __builtin_amdgcn_mfma_f32_16x16x32_bf16((a_).s, (b_).s, (c_), 0, 0, 0)

// 3-product split matvec for one row-tile, el multiply, freeze-mask select
#define MME(AH0, AH1, AL0, AL1, ELV, UD) do { \
    f32x4 accA = MFMA(AH0, BH0, zz); \
    accA = MFMA(AH1, BH1, accA); \
    accA = MFMA(AH0, BL0, accA); \
    f32x4 accB = MFMA(AH1, BL1, zz); \
    accB = MFMA(AL0, BH0, accB); \
    accB = MFMA(AL1, BH1, accB); \
    f32x4 un = (accA + accB) * (ELV); \
    (UD).x = act ? un.x : (UD).x; \
    (UD).y = act ? un.y : (UD).y; \
    (UD).z = act ? un.z : (UD).z; \
    (UD).w = act ? un.w : (UD).w; \
} while (0)

#define LOADL(D0, D1, D2, D3, tt) do { \
    const float* lp_ = lg + (size_t)(tt) * 64 + 4*gq; \
    (D0) = *(const f32x4*)(lp_); \
    (D1) = *(const f32x4*)(lp_ + 16); \
    (D2) = *(const f32x4*)(lp_ + 32); \
    (D3) = *(const f32x4*)(lp_ + 48); \
} while (0)

#define WSUM(x) do { _Pragma("unroll") \
    for (int off_ = 32; off_; off_ >>= 1) (x) += __shfl_xor((x), off_); } while (0)

__global__ __launch_bounds__(64, 1)
void crf_seg_kernel(const float* __restrict__ logits,
                    const float* __restrict__ Tm,
                    const int*   __restrict__ mask_g,
                    double*      __restrict__ ws,
                    int S)
{
    const int blk = blockIdx.x;
    const int b   = blk >> 1;              // 2 waves per sequence
    const int wv  = blk & 1;
    const int l   = threadIdx.x;
    const int cl  = l & 15;                // local chain / fragment column
    const int gq  = l >> 4;                // lane group
    const int c   = 16 * wv + cl;          // global segment 0..31
    constexpr int L = 66, START = 64, END = 65;
    const float SC = 0.0078125f;           // 2^-7, exact

    __shared__ float Ub[16 * 68];          // [chain][state], stride-68 pad

    const float* lg  = logits + (size_t)b * S * 64;
    const int*   msk = mask_g + (size_t)b * S;

    int lensum = 0;
    #pragma unroll 4
    for (int t0 = l; t0 < S; t0 += 64) lensum += msk[t0];
    WSUM(lensum);
    const int len = lensum, NP = len - 1;
    const int n = (NP + PSEG - 1) / PSEG;
    int spanv = NP - c * n;
    spanv = (spanv < 0) ? 0 : ((spanv > n) ? n : spanv);
    const int endv = (c == 0) ? n : (BURN + spanv);   // active iters
    const int toff = (c == 0) ? 1 : (c * n - (BURN - 1));
    const int I = n + BURN;
    const bool lastc = (c * n < NP) && ((c + 1) * n >= NP);  // last non-empty

    // E fragments: 4 row-tiles x 2 k-tiles, hi/lo
    FRAG ah00, ah01, ah10, ah11, ah20, ah21, ah30, ah31;
    FRAG al00, al01, al10, al11, al20, al21, al30, al31;
    BUILD_A(0, 0, ah00, al00); BUILD_A(0, 1, ah01, al01);
    BUILD_A(1, 0, ah10, al10); BUILD_A(1, 1, ah11, al11);
    BUILD_A(2, 0, ah20, al20); BUILD_A(2, 1, ah21, al21);
    BUILD_A(3, 0, ah30, al30); BUILD_A(3, 1, ah31, al31);

    // state init: chain 0 = exact t=0 init; others = all-ones seed
    f32x4 U0, U1, U2, U3;
    {
        const bool c0 = (c == 0);
        #define INITU(mm, UD) do { \
            int r0 = 16*(mm) + 4*gq; \
            (UD).x = c0 ? __builtin_amdgcn_exp2f((lg[r0+0] + Tm[(r0+0)*L + START]) * LOG2E) : 1.0f; \
            (UD).y = c0 ? __builtin_amdgcn_exp2f((lg[r0+1] + Tm[(r0+1)*L + START]) * LOG2E) : 1.0f; \
            (UD).z = c0 ? __builtin_amdgcn_exp2f((lg[r0+2] + Tm[(r0+2)*L + START]) * LOG2E) : 1.0f; \
            (UD).w = c0 ? __builtin_amdgcn_exp2f((lg[r0+3] + Tm[(r0+3)*L + START]) * LOG2E) : 1.0f; \
        } while (0)
        INITU(0, U0); INITU(1, U1); INITU(2, U2); INITU(3, U3);
    }

    int    M2    = 0;
    float  sslog = 0.0f;
    f32x4  cA0, cA1, cA2, cA3, cB0, cB1, cB2, cB3;
    {
        int t0v = toff;     t0v = (t0v > NP) ? NP : t0v;
        int t1v = toff + 1; t1v = (t1v > NP) ? NP : t1v;
        LOADL(cA0, cA1, cA2, cA3, t0v);
        LOADL(cB0, cB1, cB2, cB3, t1v);
    }
    const f32x4 zz = {0.f, 0.f, 0.f, 0.f};

    #pragma clang loop unroll(disable)
    for (int i = 0; i < I; ++i) {
        // prefetch logits for i+2 (per-lane t)
        int tld = toff + i + 2; tld = (tld > NP) ? NP : tld;
        f32x4 p0, p1, p2, p3;
        LOADL(p0, p1, p2, p3, tld);

        const bool act = (i < endv);

        // el = exp(logits[t])
        f32x4 e0v, e1v, e2v, e3v;
        EXPV(e0v, cA0); EXPV(e1v, cA1); EXPV(e2v, cA2); EXPV(e3v, cA3);

        // U -> LDS (D layout) then read in B-fragment order
        *(f32x4*)&Ub[cl*68 +  0 + 4*gq] = U0;
        *(f32x4*)&Ub[cl*68 + 16 + 4*gq] = U1;
        *(f32x4*)&Ub[cl*68 + 32 + 4*gq] = U2;
        *(f32x4*)&Ub[cl*68 + 48 + 4*gq] = U3;
        f32x4 qa0 = *(const f32x4*)&Ub[cl*68 +      8*gq];
        f32x4 qb0 = *(const f32x4*)&Ub[cl*68 +  4 + 8*gq];
        f32x4 qa1 = *(const f32x4*)&Ub[cl*68 + 32 + 8*gq];
        f32x4 qb1 = *(const f32x4*)&Ub[cl*68 + 36 + 8*gq];
        FRAG BH0, BL0, BH1, BL1;
        SPLIT8(qa0, qb0, BH0, BL0);
        SPLIT8(qa1, qb1, BH1, BL1);

        MME(ah00, ah01, al00, al01, e0v, U0);
        MME(ah10, ah11, al10, al11, e1v, U1);
        MME(ah20, ah21, al20, al21, e2v, U2);
        MME(ah30, ah31, al30, al31, e3v, U3);

        if ((i & 3) == 3) {      // exact power-of-2 renorm, per chain
            int rb = __builtin_amdgcn_ds_bpermute(cl << 2, __float_as_int(U0.x));
            unsigned eb = ((unsigned)rb >> 23) & 0xffu;
            int e = (int)eb - 127;
            float mlt = __uint_as_float((unsigned)(254 - (int)eb) << 23);
            U0 *= mlt; U1 *= mlt; U2 *= mlt; U3 *= mlt;
            bool cnt = (c == 0) || (i >= BURN);
            M2 += cnt ? e : 0;
        }
        if (i == BURN - 1) {     // reference scale at segment start (c>0)
            float ps = U0.x+U0.y+U0.z+U0.w + U1.x+U1.y+U1.z+U1.w
                     + U2.x+U2.y+U2.z+U2.w + U3.x+U3.y+U3.z+U3.w;
            ps += __shfl_xor(ps, 16); ps += __shfl_xor(ps, 32);
            sslog = __builtin_amdgcn_logf(ps);
        }

        cA0 = cB0; cA1 = cB1; cA2 = cB2; cA3 = cB3;
        cB0 = p0;  cB1 = p1;  cB2 = p2;  cB3 = p3;
    }

    // final combine factor e^{T[end,row]} for the LAST NON-EMPTY segment
    {
        const bool lc = lastc;
        #define ENDF(mm, UD) do { \
            int r0 = 16*(mm) + 4*gq; \
            (UD).x *= lc ? __builtin_amdgcn_exp2f(Tm[END*L + r0+0] * LOG2E) : 1.0f; \
            (UD).y *= lc ? __builtin_amdgcn_exp2f(Tm[END*L + r0+1] * LOG2E) : 1.0f; \
            (UD).z *= lc ? __builtin_amdgcn_exp2f(Tm[END*L + r0+2] * LOG2E) : 1.0f; \
            (UD).w *= lc ? __builtin_amdgcn_exp2f(Tm[END*L + r0+3] * LOG2E) : 1.0f; \
        } while (0)
        ENDF(0, U0); ENDF(1, U1); ENDF(2, U2); ENDF(3, U3);
    }
    float Sv = U0.x+U0.y+U0.z+U0.w + U1.x+U1.y+U1.z+U1.w
             + U2.x+U2.y+U2.z+U2.w + U3.x+U3.y+U3.z+U3.w;
    Sv += __shfl_xor(Sv, 16); Sv += __shfl_xor(Sv, 32);

    double G = (double)M2 + 7.0 * (double)spanv
             + (double)__builtin_amdgcn_logf(Sv);
    if (c > 0) G -= (double)sslog;
    if (l < 16) ws[(size_t)b * PSEG + c] = G;
}

// gold score + combine the 32 partials; 4 sequences per block (1 per wave)
__global__ __launch_bounds__(256, 4)
void crf_fin_kernel(const float* __restrict__ logits,
                    const float* __restrict__ Tm,
                    const int*   __restrict__ labels,
                    const int*   __restrict__ mask_g,
                    const double* __restrict__ ws,
                    float* __restrict__ out,
                    int S, int B)
{
    const int wid = threadIdx.x >> 6;
    const int j   = threadIdx.x & 63;
    const int b   = (blockIdx.x << 2) | wid;
    if (b >= B) return;
    constexpr int L = 66, START = 64, END = 65;
    const float* lg  = logits + (size_t)b * S * 64;
    const int*   lab = labels + (size_t)b * S;
    const int*   msk = mask_g + (size_t)b * S;

    int   lensum = 0;
    float gsum   = 0.0f;
    #pragma unroll 4
    for (int t0 = j; t0 < S; t0 += 64) {
        if (msk[t0]) {
            ++lensum;
            int lc = lab[t0];
            float ga = lg[(size_t)t0 * 64 + lc];
            if (t0 > 0) ga += Tm[lc * L + lab[t0 - 1]];
            gsum += ga;
        }
    }
    WSUM(lensum);
    WSUM(gsum);
    if (j == 0) {
        const int len = lensum;
        double Gt = 0.0;
        #pragma unroll
        for (int q = 0; q < PSEG; ++q) Gt += ws[(size_t)b * PSEG + q];
        int lab0 = lab[0];
        int labl = lab[len - 1];
        float goldall = gsum + Tm[lab0 * L + START] + Tm[END * L + labl];
        out[b] = (float)(Gt * LN2 - (double)goldall);
    }
}

extern "C" void kernel_launch(void* const* d_in, const int* in_sizes, int n_in,
                              void* d_out, int out_size, void* d_ws, size_t ws_size,
                              hipStream_t stream) {
    const float* logits = (const float*)d_in[0];
    const float* Tm     = (const float*)d_in[1];
    const int*   labels = (const int*)d_in[2];
    const int*   mask   = (const int*)d_in[3];
    float*       out    = (float*)d_out;
    double*      ws     = (double*)d_ws;

    const int B = out_size;                 // 512
    const int S = in_sizes[2] / B;          // 1024

    crf_seg_kernel<<<dim3(B * 2), dim3(64), 0, stream>>>(logits, Tm, mask, ws, S);
    crf_fin_kernel<<<dim3((B + 3) / 4), dim3(256), 0, stream>>>(logits, Tm, labels, mask, ws, out, S, B);
}